// Round 18
// baseline (24.710 us; speedup 1.0000x reference)
//
#include <hip/hip_runtime.h>

#define Bn   4
#define CIN  32
#define COUT 32
#define CG   8
#define Hh   128
#define Ww   128
#define KK   5
#define HW   (Hh * Ww)

#define TW   64     // tile 64 wide x 4 tall = 256 px per block
#define TH   4
#define PRW  68
#define PRH  8
#define NSLOT (PRW * PRH)   // 544

#define PADW 132    // padded xt2 spatial dim (2-px zero border)

typedef _Float16 h8  __attribute__((ext_vector_type(8)));
typedef float    f4  __attribute__((ext_vector_type(4)));

// main LDS layout (bytes): NO x region — A-fragments read straight from xt2.
//   w:    [2 half][25 t][4 jg][16 o] h8   : 51200  (50 x 1KB DMA chunks)
//   kern: [25 t][256 px] f16              : 12800
#define WOFF  0
#define KOFF  51200
#define SMEMB 64000

// workspace (bytes): xt2 padded [4 b][132][132][4 jg] h8
#define XT_OFF 0                       // 4*132*132*4*16 = 4,460,544
#define WT_OFF 4460544                 // 25600*2        =    51,200
#define GT_OFF 4511744                 // 4*16384*8*2    = 1,048,576
#define WS_NEED 5560320

#define GLDS(gp, lp) __builtin_amdgcn_global_load_lds( \
    (const __attribute__((address_space(1))) void*)(gp), \
    (__attribute__((address_space(3))) void*)(lp), 16, 0, 0)

// ---------- pre-pass: x (padded) / w / guide transforms + border zero ----------
__global__ __launch_bounds__(512) void prep(
    const float* __restrict__ x, const float* __restrict__ guide,
    const float* __restrict__ w,
    _Float16* __restrict__ xt, _Float16* __restrict__ wt, _Float16* __restrict__ gt)
{
    const int bid = blockIdx.x;
    const int tid = threadIdx.x;

    if (bid < 512) {
        // x[b][j][m][n] f32 -> xt2[b][m+2][n+2][32j] f16 (padded)
        const int b = bid >> 7, m = bid & 127;
        const int n = tid & 127, jh = tid >> 7;
        const float* xp = x + ((size_t)(b * CIN + jh * 8)) * HW + m * Ww + n;
        h8 v;
#pragma unroll
        for (int e = 0; e < 8; ++e) v[e] = (_Float16)xp[(size_t)e * HW];
        ((h8*)xt)[(((size_t)b * PADW + m + 2) * PADW + n + 2) * 4 + jh] = v;
    } else if (bid < 562) {
        // w -> wt[half][t][jg][o][e] f16 (LDS image)
        const int idx = (bid - 512) * 512 + tid;
        const int ht = idx >> 9;
        const int half = ht / 25, t = ht - half * 25;
        const int rem = idx & 511;
        const int jg = rem >> 7, o = (rem >> 3) & 15, e = rem & 7;
        wt[idx] = (_Float16)w[(size_t)(half * 16 + o) * (CIN * KK * KK) + (jg * 8 + e) * (KK * KK) + t];
    } else if (bid < 690) {
        // guide[b][c][m][n] f32 -> gt[b][m][n][8c] f16
        const int gr = (bid - 562) * 4 + (tid >> 7);
        const int b = gr >> 7, m = gr & 127;
        const int n = tid & 127;
        const float* gp = guide + ((size_t)b * CG) * HW + m * Ww + n;
        h8 v;
#pragma unroll
        for (int e = 0; e < 8; ++e) v[e] = (_Float16)gp[(size_t)e * HW];
        ((h8*)gt)[(size_t)b * HW + m * Ww + n] = v;
    } else {
        // zero xt2's 2-px border
        const int idx = (bid - 690) * 512 + tid;
        if (idx < 4160) {
            const int b = idx / 1040, r = idx - b * 1040;
            int mp, np;
            if (r < 528) {
                const int mr = r / 132;
                mp = (mr < 2) ? mr : mr + 128;
                np = r - mr * 132;
            } else {
                const int r2 = r - 528;
                mp = 2 + (r2 >> 2);
                const int q = r2 & 3;
                np = (q < 2) ? q : q + 128;
            }
            h8 z = {};
            h8* dst = (h8*)xt + (((size_t)b * PADW + mp) * PADW + np) * 4;
            dst[0] = z; dst[1] = z; dst[2] = z; dst[3] = z;
        }
    }
}

// ---------- main: A-operands direct from global xt2 (no x LDS), 16 waves ----------
__global__ __launch_bounds__(1024) void pac_mfma12(
    const _Float16* __restrict__ xt, const _Float16* __restrict__ wt,
    const _Float16* __restrict__ gt, const float* __restrict__ bias,
    float* __restrict__ out)
{
    __shared__ __align__(16) unsigned char smem[SMEMB];

    const int tid = threadIdx.x;
    const int bx  = blockIdx.x;        // 0..63 spatial tiles (2 wide x 32 tall)
    const int bz  = blockIdx.y;        // batch
    const int tm = (bx >> 1) * TH;
    const int tn = (bx & 1) * TW;

    const int lane = tid & 63;
    const int l15 = lane & 15, kg = lane >> 4;
    const int wv = tid >> 6;           // 16 waves

    // ---- issue w staging DMA: both halves, 50 chunks, pure linear copy ----
    for (int c = wv; c < 50; c += 16) {
        const _Float16* g = wt + (c * 64 + lane) * 8;
        GLDS(g, smem + WOFF + c * 1024);
    }

    // ---- kern compute (overlaps DMA): 4 thread-groups split the 25 taps ----
    {
        const int px = tid & 255, th = tid >> 8;   // th = 0..3
        const int lo = (th * 25) >> 2, hi = ((th + 1) * 25) >> 2;
        const int pr = px >> 6, pc = px & 63;
        const int m = tm + pr, n = tn + pc;
        const h8* gtb = (const h8*)gt + (size_t)bz * HW;
        const h8 c8 = gtb[m * Ww + n];
        float cg[8];
#pragma unroll
        for (int i = 0; i < 8; ++i) cg[i] = (float)c8[i];
        int t = 0;
#pragma unroll
        for (int k = 0; k < KK; ++k) {
#pragma unroll
            for (int l = 0; l < KK; ++l) {
                if (t >= lo && t < hi) {
                    const int gm = m + k - 2, gn = n + l - 2;
                    h8 gv = {};
                    if ((unsigned)gm < (unsigned)Hh && (unsigned)gn < (unsigned)Ww)
                        gv = gtb[gm * Ww + gn];
                    float ss = 0.f;
#pragma unroll
                    for (int i = 0; i < 8; ++i) {
                        const float d = (float)gv[i] - cg[i];
                        ss = fmaf(d, d, ss);
                    }
                    *(_Float16*)(smem + KOFF + t * 512 + px * 2) =
                        (_Float16)__expf(-0.5f * ss);
                }
                ++t;
            }
        }
    }

    __syncthreads();   // drains DMA + kern writes

    // ---- main loop: A from global xt2 (L1-hot, padded), B from LDS ----
    const int st0 = wv * 16;                   // px base
    const int r0 = wv >> 2;                    // tile row 0..3
    const int c0 = (wv & 3) * 16;              // col base 0/16/32/48

    f4 acc0 = {0.f,0.f,0.f,0.f}, acc1 = {0.f,0.f,0.f,0.f};
    const h8* xa = (const h8*)xt + ((size_t)bz * PADW * PADW) * 4;

    int t = 0;
#pragma unroll
    for (int k = 0; k < KK; ++k) {
#pragma unroll
        for (int l = 0; l < KK; ++l) {
            const int mp = tm + r0 + k;                // padded row (border cancels -2)
            const int np = tn + c0 + l15 + l;          // padded col
            h8 A0 = xa[((size_t)mp * PADW + np) * 4 + kg];
            h8 B0 = *(const h8*)(smem + WOFF + t * 1024 + kg * 256 + l15 * 16);
            h8 B1 = *(const h8*)(smem + WOFF + 25600 + t * 1024 + kg * 256 + l15 * 16);
            const _Float16 kk = *(const _Float16*)(smem + KOFF + t * 512 + (st0 + l15) * 2);

            h8 A0s = A0 * kk;                          // 4x v_pk_mul_f16, feeds both halves

            acc0 = __builtin_amdgcn_mfma_f32_16x16x32_f16(A0s, B0, acc0, 0, 0, 0);
            acc1 = __builtin_amdgcn_mfma_f32_16x16x32_f16(A0s, B1, acc1, 0, 0, 0);
            ++t;
        }
    }

    const float bv0 = bias[l15], bv1 = bias[16 + l15];
#pragma unroll
    for (int i = 0; i < 4; ++i) { acc0[i] += bv0; acc1[i] += bv1; }

    // ---- transpose through LDS (aliases w region) for dense stores ----
    __syncthreads();
    float* outst = (float*)smem;               // [32 o][260 px] = 33280 B
    *(f4*)(outst + l15 * 260 + st0 + kg * 4) = acc0;
    *(f4*)(outst + (16 + l15) * 260 + st0 + kg * 4) = acc1;
    __syncthreads();

    const int o = tid >> 5;                    // 0..31
    const int p = (tid & 31) * 8;              // 0..248
    const int row = p >> 6, col = p & 63;
    float* op = out + ((size_t)(bz * COUT + o)) * HW + (size_t)(tm + row) * Ww + tn + col;
    const float* src = outst + o * 260 + p;
    *(f4*)op = *(const f4*)src;
    *(f4*)(op + 4) = *(const f4*)(src + 4);
}

// ---------- fallback (R6 kernel, used only if ws_size too small) ----------
typedef _Float16 h4v __attribute__((ext_vector_type(4)));
#define FXOFF  0
#define FXJG   8704
#define FWOFF  34816
#define FKOFF  60416
__global__ __launch_bounds__(512, 4) void pac_mfma2(
    const float* __restrict__ x, const float* __restrict__ guide,
    const float* __restrict__ weight, const float* __restrict__ bias,
    float* __restrict__ out)
{
    __shared__ __align__(16) unsigned char smem[73216];
    const int tid  = threadIdx.x;
    const int bx   = blockIdx.x;
    const int half = blockIdx.y;
    const int bz   = blockIdx.z;
    const int tm = (bx >> 1) * TH;
    const int tn = (bx & 1) * TW;

    const float* xb = x + (size_t)bz * CIN * HW;
#pragma unroll
    for (int it = 0; it < 34; ++it) {
        const int idx  = it * 512 + tid;
        const int j    = idx / NSLOT;
        const int slot = idx - j * NSLOT;
        const int r    = slot / PRW;
        const int c    = slot - r * PRW;
        const int gm = tm + r - 2, gn = tn + c - 2;
        float v = 0.f;
        if ((unsigned)gm < (unsigned)Hh && (unsigned)gn < (unsigned)Ww)
            v = xb[(size_t)j * HW + gm * Ww + gn];
        *(_Float16*)(smem + FXOFF + (j >> 3) * FXJG + slot * 16 + (j & 7) * 2) = (_Float16)v;
    }
#pragma unroll
    for (int it = 0; it < 25; ++it) {
        const int idx = it * 512 + tid;
        const int o = idx & 15;
        const int j = (idx >> 4) & 31;
        const int t = idx >> 9;
        const float v = weight[(size_t)(half * 16 + o) * (CIN * KK * KK) + j * (KK * KK) + t];
        *(_Float16*)(smem + FWOFF + t * 1024 + (j >> 3) * 256 + o * 16 + (j & 7) * 2) = (_Float16)v;
    }
    {
        const int px = tid & 255, th = tid >> 8;
        const int pr = px >> 6, pc = px & 63;
        const int m = tm + pr, n = tn + pc;
        const float* gb = guide + ((size_t)bz * CG) * HW + m * Ww + n;
        float center[CG];
#pragma unroll
        for (int c = 0; c < CG; ++c) center[c] = gb[c * HW];
        int t = 0;
#pragma unroll
        for (int k = 0; k < KK; ++k) {
            const int dm = k - 2;
            const bool rowok = ((unsigned)(m + dm) < (unsigned)Hh);
#pragma unroll
            for (int l = 0; l < KK; ++l) {
                if ((t < 13) == (th == 0)) {
                    const int dn = l - 2;
                    const bool ok = rowok && ((unsigned)(n + dn) < (unsigned)Ww);
                    float ss = 0.f;
#pragma unroll
                    for (int c = 0; c < CG; ++c) {
                        float gv = ok ? gb[c * HW + dm * Ww + dn] : 0.f;
                        float d = gv - center[c];
                        ss = fmaf(d, d, ss);
                    }
                    *(_Float16*)(smem + FKOFF + t * 512 + px * 2) = (_Float16)__expf(-0.5f * ss);
                }
                ++t;
            }
        }
    }
    __syncthreads();
    const int lane = tid & 63;
    const int l15 = lane & 15, kg = lane >> 4;
    const int wv = tid >> 6;
    const int st0 = wv * 32, st1 = st0 + 16;
    const int r0 = wv >> 1;
    const int c00 = (wv & 1) * 32;
    f4 acc0 = {0.f, 0.f, 0.f, 0.f}, acc1 = {0.f, 0.f, 0.f, 0.f};
    const unsigned char* xg = smem + FXOFF + kg * FXJG;
    const float bv = bias[half * 16 + l15];
    int t = 0;
#pragma unroll
    for (int k = 0; k < KK; ++k) {
#pragma unroll
        for (int l = 0; l < KK; ++l) {
            const int abase = ((r0 + k) * PRW + c00 + l + l15) * 16;
            h8 A0 = *(const h8*)(xg + abase);
            h8 A1 = *(const h8*)(xg + abase + 256);
            h8 Bv = *(const h8*)(smem + FWOFF + t * 1024 + kg * 256 + l15 * 16);
            f4 p0 = __builtin_amdgcn_mfma_f32_16x16x32_f16(A0, Bv, (f4){0.f,0.f,0.f,0.f}, 0, 0, 0);
            f4 p1 = __builtin_amdgcn_mfma_f32_16x16x32_f16(A1, Bv, (f4){0.f,0.f,0.f,0.f}, 0, 0, 0);
            h4v k0 = *(const h4v*)(smem + FKOFF + t * 512 + (st0 + kg * 4) * 2);
            h4v k1 = *(const h4v*)(smem + FKOFF + t * 512 + (st1 + kg * 4) * 2);
#pragma unroll
            for (int i = 0; i < 4; ++i) {
                acc0[i] = fmaf((float)k0[i], p0[i], acc0[i]);
                acc1[i] = fmaf((float)k1[i], p1[i], acc1[i]);
            }
            ++t;
        }
    }
#pragma unroll
    for (int i = 0; i < 4; ++i) { acc0[i] += bv; acc1[i] += bv; }
    __syncthreads();
    float* outst = (float*)smem;
    *(f4*)(outst + l15 * 260 + st0 + kg * 4) = acc0;
    *(f4*)(outst + l15 * 260 + st1 + kg * 4) = acc1;
    __syncthreads();
    const int o = tid >> 5;
    const int p = (tid & 31) * 8;
    f4 v0 = *(const f4*)(outst + o * 260 + p);
    f4 v1 = *(const f4*)(outst + o * 260 + p + 4);
    const int mr = p >> 6, nc = p & 63;
    float* op = out + ((size_t)(bz * COUT + half * 16 + o)) * HW + (size_t)(tm + mr) * Ww + tn + nc;
    *(f4*)op = v0;
    *(f4*)(op + 4) = v1;
}

extern "C" void kernel_launch(void* const* d_in, const int* in_sizes, int n_in,
                              void* d_out, int out_size, void* d_ws, size_t ws_size,
                              hipStream_t stream) {
    const float* x      = (const float*)d_in[0];
    const float* guide  = (const float*)d_in[1];
    const float* weight = (const float*)d_in[2];
    const float* bias   = (const float*)d_in[3];
    float* out = (float*)d_out;

    if (ws_size >= (size_t)WS_NEED) {
        _Float16* xt = (_Float16*)((char*)d_ws + XT_OFF);
        _Float16* wt = (_Float16*)((char*)d_ws + WT_OFF);
        _Float16* gt = (_Float16*)((char*)d_ws + GT_OFF);
        prep<<<dim3(699), 512, 0, stream>>>(x, guide, weight, xt, wt, gt);
        pac_mfma12<<<dim3(64, Bn), 1024, 0, stream>>>(xt, wt, gt, bias, out);
    } else {
        pac_mfma2<<<dim3(64, 2, Bn), 512, 0, stream>>>(x, guide, weight, bias, out);
    }
}

// Round 19
// 23.271 us; speedup vs baseline: 1.0618x; 1.0618x over previous
//
#include <hip/hip_runtime.h>

#define Bn   4
#define CIN  32
#define COUT 32
#define CG   8
#define Hh   128
#define Ww   128
#define KK   5
#define HW   (Hh * Ww)

#define TW   64     // tile 64 wide x 4 tall = 256 px per block
#define TH   4
#define PRW  68     // halo 68 x 8
#define PRH  8
#define NSLOT (PRW * PRH)   // 544

typedef _Float16 h8  __attribute__((ext_vector_type(8)));
typedef _Float16 h2  __attribute__((ext_vector_type(2)));
typedef float    f4  __attribute__((ext_vector_type(4)));

// LDS layout (bytes) — SoA over j-octets: fragment reads have 16B lane stride.
//   x:    [4 jg][544 slots] h8            : 34816  (aliased by out-stage in epilogue)
//   w h0: [25 t][4 jg][16 o] h8           : 25600  (half1 read as B1r from wt)
//   kern: [25 t][8 g][16 i] u32-pairs     : 12800
#define XOFF  0
#define XJG   8704
#define WOFF  34816
#define KOFF  60416
#define SMEMB 73216

// workspace (bytes)
#define XT_OFF 0                       // 4*16384*32*2 = 4,194,304
#define WT_OFF 4194304                 // 25600*2      =    51,200
#define GT_OFF 4245504                 // 4*16384*8*2  = 1,048,576
#define WS_NEED 5294080

// ---------- pre-pass: x/w/guide layout transforms ----------
__global__ __launch_bounds__(512) void prep(
    const float* __restrict__ x, const float* __restrict__ guide,
    const float* __restrict__ w,
    _Float16* __restrict__ xt, _Float16* __restrict__ wt, _Float16* __restrict__ gt)
{
    const int bid = blockIdx.x;
    const int tid = threadIdx.x;

    if (bid < 512) {
        // x[b][j][m][n] f32 -> xt[b][m][n][32j] f16
        const int b = bid >> 7, m = bid & 127;
        const int n = tid & 127, jh = tid >> 7;
        const float* xp = x + ((size_t)(b * CIN + jh * 8)) * HW + m * Ww + n;
        h8 v;
#pragma unroll
        for (int e = 0; e < 8; ++e) v[e] = (_Float16)xp[(size_t)e * HW];
        ((h8*)xt)[((size_t)b * HW + m * Ww + n) * 4 + jh] = v;
    } else if (bid < 562) {
        // w -> wt[half][t][jg][o][e] f16 (LDS image)
        const int idx = (bid - 512) * 512 + tid;
        const int ht = idx >> 9;
        const int half = ht / 25, t = ht - half * 25;
        const int rem = idx & 511;
        const int jg = rem >> 7, o = (rem >> 3) & 15, e = rem & 7;
        wt[idx] = (_Float16)w[(size_t)(half * 16 + o) * (CIN * KK * KK) + (jg * 8 + e) * (KK * KK) + t];
    } else {
        // guide[b][c][m][n] f32 -> gt[b][m][n][8c] f16
        const int gr = (bid - 562) * 4 + (tid >> 7);
        const int b = gr >> 7, m = gr & 127;
        const int n = tid & 127;
        const float* gp = guide + ((size_t)b * CG) * HW + m * Ww + n;
        h8 v;
#pragma unroll
        for (int e = 0; e < 8; ++e) v[e] = (_Float16)gp[(size_t)e * HW];
        ((h8*)gt)[(size_t)b * HW + m * Ww + n] = v;
    }
}

// ---------- main kernel: merged-o, in-main kern from gt, MFMA tap loop ----------
__global__ __launch_bounds__(512, 2) void pac_mfma7(
    const _Float16* __restrict__ xt, const _Float16* __restrict__ wt,
    const _Float16* __restrict__ gt, const float* __restrict__ bias,
    float* __restrict__ out)
{
    __shared__ __align__(16) unsigned char smem[SMEMB];

    const int tid = threadIdx.x;
    const int bx  = blockIdx.x;        // 0..63 spatial tiles (2 wide x 32 tall)
    const int bz  = blockIdx.y;        // batch
    const int tm = (bx >> 1) * TH;
    const int tn = (bx & 1) * TW;

    const int lane = tid & 63;
    const int l15 = lane & 15, kg = lane >> 4;

    // ---- preload half1 B-fragments (global wt, L2-hot; issues first) ----
    const h8* wh1 = (const h8*)wt + 1600;      // half1 = elements [12800,25600)
    h8 B1r[25];
#pragma unroll
    for (int t = 0; t < 25; ++t)
        B1r[t] = wh1[t * 64 + kg * 16 + l15];

    // ---- stage x: 544 slots x 4 j-octets, b128 in / b128 out ----
    const int pxbase = bz * HW;
#pragma unroll
    for (int it = 0; it < 5; ++it) {
        const int idx = it * 512 + tid;            // over 2176 = 544*4
        if (idx < 2176) {
            const int slot = idx >> 2, jg = idx & 3;
            const int r = slot / PRW;
            const int c = slot - r * PRW;
            const int gm = tm + r - 2, gn = tn + c - 2;
            h8 v = {};
            if ((unsigned)gm < (unsigned)Hh && (unsigned)gn < (unsigned)Ww)
                v = *(const h8*)(xt + ((size_t)(pxbase + gm * Ww + gn)) * 32 + jg * 8);
            *(h8*)(smem + XOFF + jg * XJG + slot * 16) = v;
        }
    }

    // ---- stage w half0: linear b128 copy ----
    const h8* wth = (const h8*)wt;
#pragma unroll
    for (int it = 0; it < 4; ++it) {
        const int idx = it * 512 + tid;            // over 1600 h8
        if (idx < 1600)
            *(h8*)(smem + WOFF + idx * 16) = wth[idx];
    }

    // ---- kern in-main: f16 gt reads (L2-hot), f32 math, pair layout ----
    {
        const int px = tid & 255, th = tid >> 8;   // th=0: taps 0..12, th=1: 13..24
        const int pr = px >> 6, pc = px & 63;
        const int pg = px >> 5, ps = (px >> 4) & 1, pi = px & 15;   // pair coords
        const int m = tm + pr, n = tn + pc;
        const h8* gtb = (const h8*)gt + (size_t)bz * HW;
        const h8 c8 = gtb[m * Ww + n];
        float cg[8];
#pragma unroll
        for (int i = 0; i < 8; ++i) cg[i] = (float)c8[i];
        int t = 0;
#pragma unroll
        for (int k = 0; k < KK; ++k) {
#pragma unroll
            for (int l = 0; l < KK; ++l) {
                if ((t < 13) == (th == 0)) {
                    const int gm = m + k - 2, gn = n + l - 2;
                    h8 gv = {};
                    if ((unsigned)gm < (unsigned)Hh && (unsigned)gn < (unsigned)Ww)
                        gv = gtb[gm * Ww + gn];
                    float ss = 0.f;
#pragma unroll
                    for (int i = 0; i < 8; ++i) {
                        const float d = (float)gv[i] - cg[i];
                        ss = fmaf(d, d, ss);
                    }
                    // pair layout: (kern[t][pg*32+pi], kern[t][pg*32+16+pi])
                    *(_Float16*)(smem + KOFF + t * 512 + ((pg * 16 + pi) * 2 + ps) * 2) =
                        (_Float16)__expf(-0.5f * ss);
                }
                ++t;
            }
        }
    }

    __syncthreads();

    // ---- main loop: scale A once, 4 MFMA chains (2 subtiles x 2 o-halves) ----
    const int wv = tid >> 6;                   // 8 waves
    const int st0 = wv * 32, st1 = st0 + 16;   // two 16-px M-subtiles (same row)
    const int r0 = wv >> 1;                    // tile row 0..3
    const int c00 = (wv & 1) * 32;             // col base 0/32

    f4 acc00 = {0.f,0.f,0.f,0.f}, acc01 = {0.f,0.f,0.f,0.f};
    f4 acc10 = {0.f,0.f,0.f,0.f}, acc11 = {0.f,0.f,0.f,0.f};
    const unsigned char* xg = smem + XOFF + kg * XJG;
    const int kbase = KOFF + (wv * 16 + l15) * 4;   // this lane's kern pair column

    int t = 0;
#pragma unroll
    for (int k = 0; k < KK; ++k) {
#pragma unroll
        for (int l = 0; l < KK; ++l) {
            const int abase = ((r0 + k) * PRW + c00 + l + l15) * 16;
            h8 A0 = *(const h8*)(xg + abase);
            h8 A1 = *(const h8*)(xg + abase + 256);        // +16 cols
            h8 B0 = *(const h8*)(smem + WOFF + t * 1024 + kg * 256 + l15 * 16);
            h2 kk = *(const h2*)(smem + kbase + t * 512);  // (kern[px0], kern[px1])

            h8 A0s = A0 * kk[0];                           // v_pk_mul_f16
            h8 A1s = A1 * kk[1];

            acc00 = __builtin_amdgcn_mfma_f32_16x16x32_f16(A0s, B0,     acc00, 0, 0, 0);
            acc01 = __builtin_amdgcn_mfma_f32_16x16x32_f16(A0s, B1r[t], acc01, 0, 0, 0);
            acc10 = __builtin_amdgcn_mfma_f32_16x16x32_f16(A1s, B0,     acc10, 0, 0, 0);
            acc11 = __builtin_amdgcn_mfma_f32_16x16x32_f16(A1s, B1r[t], acc11, 0, 0, 0);
            ++t;
        }
    }

    const float bv0 = bias[l15], bv1 = bias[16 + l15];
#pragma unroll
    for (int i = 0; i < 4; ++i) {
        acc00[i] += bv0; acc10[i] += bv0;
        acc01[i] += bv1; acc11[i] += bv1;
    }

    // ---- transpose through LDS (aliases x region) for dense stores ----
    __syncthreads();
    float* outst = (float*)smem;               // [32 o][260 px] = 33280 B
    *(f4*)(outst + l15 * 260 + st0 + kg * 4) = acc00;
    *(f4*)(outst + l15 * 260 + st1 + kg * 4) = acc10;
    *(f4*)(outst + (16 + l15) * 260 + st0 + kg * 4) = acc01;
    *(f4*)(outst + (16 + l15) * 260 + st1 + kg * 4) = acc11;
    __syncthreads();

    const int o = tid >> 4;                    // 0..31
    const int i = tid & 15;
    float* op = out + ((size_t)(bz * COUT + o)) * HW;
#pragma unroll
    for (int c = 0; c < 4; ++c) {              // 4 rows of the tile
        f4 v = *(const f4*)(outst + o * 260 + c * 64 + i * 4);
        *(f4*)(op + (size_t)(tm + c) * Ww + tn + i * 4) = v;
    }
}

// ---------- fallback (R6 kernel, used only if ws_size too small) ----------
typedef _Float16 h4v __attribute__((ext_vector_type(4)));
__global__ __launch_bounds__(512, 4) void pac_mfma2(
    const float* __restrict__ x, const float* __restrict__ guide,
    const float* __restrict__ weight, const float* __restrict__ bias,
    float* __restrict__ out)
{
    __shared__ __align__(16) unsigned char smem[SMEMB];
    const int tid  = threadIdx.x;
    const int bx   = blockIdx.x;
    const int half = blockIdx.y;
    const int bz   = blockIdx.z;
    const int tm = (bx >> 1) * TH;
    const int tn = (bx & 1) * TW;

    const float* xb = x + (size_t)bz * CIN * HW;
#pragma unroll
    for (int it = 0; it < 34; ++it) {
        const int idx  = it * 512 + tid;
        const int j    = idx / NSLOT;
        const int slot = idx - j * NSLOT;
        const int r    = slot / PRW;
        const int c    = slot - r * PRW;
        const int gm = tm + r - 2, gn = tn + c - 2;
        float v = 0.f;
        if ((unsigned)gm < (unsigned)Hh && (unsigned)gn < (unsigned)Ww)
            v = xb[(size_t)j * HW + gm * Ww + gn];
        *(_Float16*)(smem + XOFF + (j >> 3) * XJG + slot * 16 + (j & 7) * 2) = (_Float16)v;
    }
#pragma unroll
    for (int it = 0; it < 25; ++it) {
        const int idx = it * 512 + tid;
        const int o = idx & 15;
        const int j = (idx >> 4) & 31;
        const int t = idx >> 9;
        const float v = weight[(size_t)(half * 16 + o) * (CIN * KK * KK) + j * (KK * KK) + t];
        *(_Float16*)(smem + WOFF + t * 1024 + (j >> 3) * 256 + o * 16 + (j & 7) * 2) = (_Float16)v;
    }
    {
        const int px = tid & 255, th = tid >> 8;
        const int pr = px >> 6, pc = px & 63;
        const int m = tm + pr, n = tn + pc;
        const float* gb = guide + ((size_t)bz * CG) * HW + m * Ww + n;
        float center[CG];
#pragma unroll
        for (int c = 0; c < CG; ++c) center[c] = gb[c * HW];
        int t = 0;
#pragma unroll
        for (int k = 0; k < KK; ++k) {
            const int dm = k - 2;
            const bool rowok = ((unsigned)(m + dm) < (unsigned)Hh);
#pragma unroll
            for (int l = 0; l < KK; ++l) {
                if ((t < 13) == (th == 0)) {
                    const int dn = l - 2;
                    const bool ok = rowok && ((unsigned)(n + dn) < (unsigned)Ww);
                    float ss = 0.f;
#pragma unroll
                    for (int c = 0; c < CG; ++c) {
                        float gv = ok ? gb[c * HW + dm * Ww + dn] : 0.f;
                        float d = gv - center[c];
                        ss = fmaf(d, d, ss);
                    }
                    *(_Float16*)(smem + KOFF + t * 512 + px * 2) = (_Float16)__expf(-0.5f * ss);
                }
                ++t;
            }
        }
    }
    __syncthreads();
    const int lane = tid & 63;
    const int l15 = lane & 15, kg = lane >> 4;
    const int wv = tid >> 6;
    const int st0 = wv * 32, st1 = st0 + 16;
    const int r0 = wv >> 1;
    const int c00 = (wv & 1) * 32;
    f4 acc0 = {0.f, 0.f, 0.f, 0.f}, acc1 = {0.f, 0.f, 0.f, 0.f};
    const unsigned char* xg = smem + XOFF + kg * XJG;
    const float bv = bias[half * 16 + l15];
    int t = 0;
#pragma unroll
    for (int k = 0; k < KK; ++k) {
#pragma unroll
        for (int l = 0; l < KK; ++l) {
            const int abase = ((r0 + k) * PRW + c00 + l + l15) * 16;
            h8 A0 = *(const h8*)(xg + abase);
            h8 A1 = *(const h8*)(xg + abase + 256);
            h8 Bv = *(const h8*)(smem + WOFF + t * 1024 + kg * 256 + l15 * 16);
            f4 p0 = __builtin_amdgcn_mfma_f32_16x16x32_f16(A0, Bv, (f4){0.f,0.f,0.f,0.f}, 0, 0, 0);
            f4 p1 = __builtin_amdgcn_mfma_f32_16x16x32_f16(A1, Bv, (f4){0.f,0.f,0.f,0.f}, 0, 0, 0);
            h4v k0 = *(const h4v*)(smem + KOFF + t * 512 + (st0 + kg * 4) * 2);
            h4v k1 = *(const h4v*)(smem + KOFF + t * 512 + (st1 + kg * 4) * 2);
#pragma unroll
            for (int i = 0; i < 4; ++i) {
                acc0[i] = fmaf((float)k0[i], p0[i], acc0[i]);
                acc1[i] = fmaf((float)k1[i], p1[i], acc1[i]);
            }
            ++t;
        }
    }
#pragma unroll
    for (int i = 0; i < 4; ++i) { acc0[i] += bv; acc1[i] += bv; }
    __syncthreads();
    float* outst = (float*)smem;
    *(f4*)(outst + l15 * 260 + st0 + kg * 4) = acc0;
    *(f4*)(outst + l15 * 260 + st1 + kg * 4) = acc1;
    __syncthreads();
    const int o = tid >> 5;
    const int p = (tid & 31) * 8;
    f4 v0 = *(const f4*)(outst + o * 260 + p);
    f4 v1 = *(const f4*)(outst + o * 260 + p + 4);
    const int mr = p >> 6, nc = p & 63;
    float* op = out + ((size_t)(bz * COUT + half * 16 + o)) * HW + (size_t)(tm + mr) * Ww + tn + nc;
    *(f4*)op = v0;
    *(f4*)(op + 4) = v1;
}

extern "C" void kernel_launch(void* const* d_in, const int* in_sizes, int n_in,
                              void* d_out, int out_size, void* d_ws, size_t ws_size,
                              hipStream_t stream) {
    const float* x      = (const float*)d_in[0];
    const float* guide  = (const float*)d_in[1];
    const float* weight = (const float*)d_in[2];
    const float* bias   = (const float*)d_in[3];
    float* out = (float*)d_out;

    if (ws_size >= (size_t)WS_NEED) {
        _Float16* xt = (_Float16*)((char*)d_ws + XT_OFF);
        _Float16* wt = (_Float16*)((char*)d_ws + WT_OFF);
        _Float16* gt = (_Float16*)((char*)d_ws + GT_OFF);
        prep<<<dim3(690), 512, 0, stream>>>(x, guide, weight, xt, wt, gt);
        pac_mfma7<<<dim3(64, Bn), 512, 0, stream>>>(xt, wt, gt, bias, out);
    } else {
        pac_mfma2<<<dim3(64, 2, Bn), 512, 0, stream>>>(x, guide, weight, bias, out);
    }
}